// Round 12
// baseline (739.353 us; speedup 1.0000x reference)
//
#include <hip/hip_runtime.h>

// RVQTokenizer: x[16,2048,256] f32, codebooks[4,1024,256] f32.
// Outputs (flat f32): quant[16,2048,256], indices[4,16,2048] (as float),
// 4 scalar losses (all = total vq_loss).
#define B_    16
#define T_    2048
#define D_    256
#define Q_    4
#define K_    1024
#define NTOK  (B_ * T_)            // 32768
#define QUANT_N (NTOK * D_)        // 8388608
#define IDX_N   (Q_ * NTOK)        // 131072
#define LOSS_OFF (QUANT_N + IDX_N) // 8519680
#define MARGIN_V8   0.03f          // fp32-coarse window (fallback kernel)

// u32 score-key packing: key = clamp(s*2048 + 2^21, [0, 2^22-1]) << 10 | n
// s >= -||r||^2 > -1024 guarantees positive biased value; precision 4.9e-4.
#define KSCALE 2048.0f
#define KBIAS  2097152.0f          // 1<<21
#define KMAXF  4194303.0f          // (1<<22)-1
#define MKEY   123u                // 0.06 * 2048 adjudication window (key units)

typedef __attribute__((ext_vector_type(8))) _Float16 f16x8;
typedef __attribute__((ext_vector_type(4))) _Float16 f16x4;
typedef __attribute__((ext_vector_type(4))) float    f32x4;
typedef unsigned int u32;

__device__ __forceinline__ bool lt2(float v, int k, float w, int m) {
  return v < w || (v == w && k < m);
}
__device__ __forceinline__ u32 umn(u32 a, u32 b) { return a < b ? a : b; }
__device__ __forceinline__ u32 umx(u32 a, u32 b) { return a > b ? a : b; }

// insert key into sorted min-3 (t0<=t1<=t2): 5 min/max ops
__device__ __forceinline__ void kins3(u32& t0, u32& t1, u32& t2, u32 key) {
  u32 m0 = umx(t0, key); t0 = umn(t0, key);
  u32 m1 = umx(t1, m0);  t1 = umn(t1, m0);
  t2 = umn(t2, m1);
}

__device__ __forceinline__ void gload_lds16(const _Float16* g, _Float16* l) {
  __builtin_amdgcn_global_load_lds(
      (const __attribute__((address_space(1))) void*)g,
      (__attribute__((address_space(3))) void*)l, 16, 0, 0);
}

// ---------------------------------------------------------------------------
// Bit-exact numpy emulation (verified PASS in rounds 8-11).
template <typename F>
__device__ __forceinline__ float np_sum256(F p) {
  float half[2];
#pragma unroll
  for (int h = 0; h < 2; ++h) {
    const int base = h * 128;
    float s[16];
#pragma unroll
    for (int l = 0; l < 16; ++l) {
      float t01 = __fadd_rn(p(base + l),      p(base + 16 + l));
      float t23 = __fadd_rn(p(base + 32 + l), p(base + 48 + l));
      float t45 = __fadd_rn(p(base + 64 + l), p(base + 80 + l));
      float t67 = __fadd_rn(p(base + 96 + l), p(base + 112 + l));
      s[l] = __fadd_rn(__fadd_rn(t01, t23), __fadd_rn(t45, t67));
    }
#pragma unroll
    for (int w = 8; w >= 1; w >>= 1)
#pragma unroll
      for (int l = 0; l < w; ++l) s[l] = __fadd_rn(s[l], s[l + w]);
    half[h] = s[0];
  }
  return __fadd_rn(half[0], half[1]);
}

template <typename F>
__device__ __forceinline__ float np_einsum256(F p) {
  float v[4] = {0.f, 0.f, 0.f, 0.f};
#pragma unroll
  for (int c = 0; c < 16; ++c) {
#pragma unroll
    for (int l = 0; l < 4; ++l) {
      int d0 = c * 16 + l;
      float t = __fadd_rn(p(d0 + 12), v[l]);
      t = __fadd_rn(p(d0 + 8), t);
      t = __fadd_rn(p(d0 + 4), t);
      v[l] = __fadd_rn(p(d0), t);
    }
  }
  return __fadd_rn(__fadd_rn(v[0], v[1]), __fadd_rn(v[2], v[3]));
}

__global__ void rvq_zero(float* __restrict__ ws) { ws[0] = 0.f; }

// ---------------------------------------------------------------------------
// Prep: cn[k]=||c_k||^2 (coarse only) and fp16 codebook copy.
__global__ __launch_bounds__(256) void rvq_prep(const float* __restrict__ cb,
                                                float* __restrict__ cn,
                                                _Float16* __restrict__ cbh) {
  int k = blockIdx.x * 4 + (threadIdx.x >> 6);   // 0..4095
  int l = threadIdx.x & 63;
  const float* row = cb + (size_t)k * D_;
  float s = 0.f;
#pragma unroll
  for (int j = 0; j < 4; ++j) { float v = row[l + 64 * j]; s += v * v; }
#pragma unroll
  for (int off = 32; off; off >>= 1) s += __shfl_xor(s, off);
  if (l == 0) cn[k] = s;
  int gid = blockIdx.x * 256 + threadIdx.x;      // 0..262143
  float4 v = *(const float4*)&cb[(size_t)gid * 4];
  f16x4 h;
  h[0] = (_Float16)v.x; h[1] = (_Float16)v.y;
  h[2] = (_Float16)v.z; h[3] = (_Float16)v.w;
  *(f16x4*)&cbh[(size_t)gid * 4] = h;
}

// ---------------------------------------------------------------------------
// MFMA RVQ v3: residual in GLOBAL (quant region of out doubles as scratch);
// LDS only holds the double-buffered 16cw x 256d fp16 B panel (16 KiB) staged
// via global_load_lds with XOR-swizzle; u32-packed top-3. 4 blocks/CU.
__global__ __launch_bounds__(256, 4) void rvq_mfma3(const float* __restrict__ x,
                                                    const float* __restrict__ cb,
                                                    const float* __restrict__ cn,
                                                    const _Float16* __restrict__ cbh,
                                                    float* __restrict__ out,
                                                    float* __restrict__ loss_ws) {
  __shared__ _Float16 bpan[2][16 * 256];  // 2 x 8 KiB panels
  __shared__ int bestk[64];

  const int tid  = threadIdx.x;
  const int tok0 = blockIdx.x * 64;
  const int wv   = tid >> 6;       // wave id = M-tile (tokens wv*16..+15)
  const int l15  = tid & 15;       // A-row(token) / B-col(cw) / D-col
  const int lg   = (tid & 63) >> 4;
  const int ut   = tid >> 2, uc = tid & 3;   // streaming: 4 threads/token

  float* res = out;                // residual scratch == final quant region
  float lsq = 0.f;

  for (int q = 0; q < Q_; ++q) {
    const float*    cbq  = cb  + (size_t)q * K_ * D_;
    const float*    cnq  = cn  + (size_t)q * K_;
    const _Float16* cbhq = cbh + (size_t)q * K_ * D_;
    const float*    rsrc = (q == 0) ? x : res;

    // ---- A fragments (fp16 hi/lo) from global residual rows ---------------
    f16x8 Ah[8], Al[8];
    {
      const float* rrow = rsrc + (size_t)(tok0 + wv * 16 + l15) * D_;
#pragma unroll
      for (int ks = 0; ks < 8; ++ks) {
        float4 v0 = *(const float4*)&rrow[ks * 32 + lg * 8];
        float4 v1 = *(const float4*)&rrow[ks * 32 + lg * 8 + 4];
        float vv[8] = {v0.x, v0.y, v0.z, v0.w, v1.x, v1.y, v1.z, v1.w};
        f16x8 h, l;
#pragma unroll
        for (int j = 0; j < 8; ++j) {
          _Float16 hj = (_Float16)vv[j];
          h[j] = hj;
          l[j] = (_Float16)(vv[j] - (float)hj);
        }
        Ah[ks] = h; Al[ks] = l;
      }
    }

    // ---- top-3 u32 keys: tokens m = wv*16 + lg*4 + r ----------------------
    u32 t0[4], t1[4], t2[4];
#pragma unroll
    for (int r = 0; r < 4; ++r) { t0[r] = t1[r] = t2[r] = 0xFFFFFFFFu; }

    // stage group 0 (pre-swizzled source -> linear LDS dest)
#pragma unroll
    for (int c = 0; c < 2; ++c) {
      int s = c * 256 + tid;
      int cw = s >> 5, ch = (s & 31) ^ (cw & 7);
      gload_lds16(cbhq + (size_t)cw * D_ + ch * 8,
                  &bpan[0][(c * 256 + wv * 64) * 8]);
    }
    __syncthreads();

    for (int g = 0; g < 64; ++g) {
      if (g + 1 < 64) {
        const _Float16* gb = cbhq + (size_t)(g + 1) * 16 * D_;
#pragma unroll
        for (int c = 0; c < 2; ++c) {
          int s = c * 256 + tid;
          int cw = s >> 5, ch = (s & 31) ^ (cw & 7);
          gload_lds16(gb + (size_t)cw * D_ + ch * 8,
                      &bpan[(g + 1) & 1][(c * 256 + wv * 64) * 8]);
        }
      }
      const _Float16* P = bpan[g & 1];
      f16x8 b[8];
#pragma unroll
      for (int ks = 0; ks < 8; ++ks)
        b[ks] = *(const f16x8*)&P[l15 * 256 + (((ks * 4 + lg) ^ (l15 & 7)) * 8)];

      f32x4 h0 = {0.f,0.f,0.f,0.f}, h1 = {0.f,0.f,0.f,0.f};
      f32x4 lo0 = {0.f,0.f,0.f,0.f}, lo1 = {0.f,0.f,0.f,0.f};
#pragma unroll
      for (int ks = 0; ks < 4; ++ks) {
        h0  = __builtin_amdgcn_mfma_f32_16x16x32_f16(Ah[ks],     b[ks],     h0,  0, 0, 0);
        h1  = __builtin_amdgcn_mfma_f32_16x16x32_f16(Ah[ks + 4], b[ks + 4], h1,  0, 0, 0);
        lo0 = __builtin_amdgcn_mfma_f32_16x16x32_f16(Al[ks],     b[ks],     lo0, 0, 0, 0);
        lo1 = __builtin_amdgcn_mfma_f32_16x16x32_f16(Al[ks + 4], b[ks + 4], lo1, 0, 0, 0);
      }
      const int n = g * 16 + l15;
      float c2b = __builtin_fmaf(cnq[n], KSCALE, KBIAS);
#pragma unroll
      for (int r = 0; r < 4; ++r) {
        float sum = (h0[r] + h1[r]) + (lo0[r] + lo1[r]);
        float kf = __builtin_fmaf(sum, -2.f * KSCALE, c2b);
        u32 kv = (u32)fminf(fmaxf(kf, 0.f), KMAXF);
        kins3(t0[r], t1[r], t2[r], (kv << 10) | (u32)n);
      }
      __syncthreads();    // drains stage(g+1); protects buffer reuse
    }

    // ---- merge top-3 across the 16 l15 lanes ------------------------------
#pragma unroll
    for (int r = 0; r < 4; ++r) {
#pragma unroll
      for (int off = 1; off < 16; off <<= 1) {
        u32 o0 = (u32)__shfl_xor((int)t0[r], off);
        u32 o1 = (u32)__shfl_xor((int)t1[r], off);
        u32 o2 = (u32)__shfl_xor((int)t2[r], off);
        kins3(t0[r], t1[r], t2[r], o0);
        kins3(t0[r], t1[r], t2[r], o1);
        kins3(t0[r], t1[r], t2[r], o2);
      }
    }

    // ---- leaders adjudicate (np-bit-exact) + write indices ----------------
    if (l15 == 0) {
#pragma unroll
      for (int r = 0; r < 4; ++r) {
        int t = wv * 16 + lg * 4 + r;
        int kk = (int)(t0[r] & 1023u);
        u32 s0 = t0[r] >> 10, s1 = t1[r] >> 10, s2 = t2[r] >> 10;
        if (s1 - s0 < MKEY) {
          const float* rsrow = rsrc + (size_t)(tok0 + t) * D_;
          float A = np_sum256([&](int d) {
            float rr = rsrow[d]; return __fmul_rn(rr, rr);
          });
          int cand[3]; int nc2 = 1;
          cand[0] = kk;
          cand[nc2++] = (int)(t1[r] & 1023u);
          if (s2 - s0 < MKEY) cand[nc2++] = (int)(t2[r] & 1023u);
          float bd = 3.4e38f; int bk2 = 0x7FFFFFFF;
          for (int i = 0; i < nc2; ++i) {
            const float* crow = cbq + (size_t)cand[i] * D_;
            float E = np_einsum256([&](int d) {
              return __fmul_rn(rsrow[d], crow[d]);
            });
            float C = np_sum256([&](int d) {
              float cc = crow[d]; return __fmul_rn(cc, cc);
            });
            float dd = __fadd_rn(__fsub_rn(A, __fmul_rn(2.f, E)), C);
            if (dd < bd || (dd == bd && cand[i] < bk2)) { bd = dd; bk2 = cand[i]; }
          }
          kk = bk2;
        }
        bestk[t] = kk;
        out[QUANT_N + (size_t)q * NTOK + tok0 + t] = (float)kk;
      }
    }
    __syncthreads();     // bestk visible

    // ---- residual update in global (+ final quant at q==3) ----------------
    {
      int kk = bestk[ut];
      const float* rrow = rsrc + (size_t)(tok0 + ut) * D_;
      const float* crow = cbq + (size_t)kk * D_;
      float* wrow = res + (size_t)(tok0 + ut) * D_;
      if (q < 3) {
#pragma unroll
        for (int j = 0; j < 16; ++j) {
          int c4 = j * 4 + uc;
          float4 rv = *(const float4*)&rrow[c4 * 4];
          float4 cv = *(const float4*)&crow[c4 * 4];
          float4 nv = {rv.x - cv.x, rv.y - cv.y, rv.z - cv.z, rv.w - cv.w};
          *(float4*)&wrow[c4 * 4] = nv;
          lsq += nv.x * nv.x + nv.y * nv.y + nv.z * nv.z + nv.w * nv.w;
        }
        __threadfence();   // res writes visible to block before next stage
      } else {
        const float* xrow = x + (size_t)(tok0 + ut) * D_;
#pragma unroll
        for (int j = 0; j < 16; ++j) {
          int c4 = j * 4 + uc;
          float4 rv = *(const float4*)&rrow[c4 * 4];
          float4 cv = *(const float4*)&crow[c4 * 4];
          float4 xv = *(const float4*)&xrow[c4 * 4];
          float4 nv = {rv.x - cv.x, rv.y - cv.y, rv.z - cv.z, rv.w - cv.w};
          lsq += nv.x * nv.x + nv.y * nv.y + nv.z * nv.z + nv.w * nv.w;
          float4 qv = {xv.x - nv.x, xv.y - nv.y, xv.z - nv.z, xv.w - nv.w};
          *(float4*)&wrow[c4 * 4] = qv;   // final quant overwrites residual
        }
      }
    }
    __syncthreads();
  }

  // ---- loss: wave reduce + one atomic per wave -----------------------------
#pragma unroll
  for (int off = 32; off; off >>= 1) lsq += __shfl_xor(lsq, off);
  if ((tid & 63) == 0) atomicAdd(loss_ws, lsq);
}

// ---------------------------------------------------------------------------
// FALLBACK (round-8 kernel, verbatim): used only if ws is too small for cbh.
__global__ __launch_bounds__(256) void rvq_cnorm(const float* __restrict__ cb,
                                                 float* __restrict__ cn) {
  int k = blockIdx.x * 4 + (threadIdx.x >> 6);
  int l = threadIdx.x & 63;
  const float* row = cb + (size_t)k * D_;
  float s = 0.f;
#pragma unroll
  for (int j = 0; j < 4; ++j) { float v = row[l + 64 * j]; s += v * v; }
#pragma unroll
  for (int off = 32; off; off >>= 1) s += __shfl_xor(s, off);
  if (l == 0) cn[k] = s;
}

__global__ __launch_bounds__(256, 2) void rvq_main_v8(const float* __restrict__ x,
                                                      const float* __restrict__ cb,
                                                      const float* __restrict__ cn,
                                                      float* __restrict__ out,
                                                      float* __restrict__ loss_ws) {
  __shared__ float4 rs4[32 * 64];
  __shared__ float4 cbt[64 * 16];
  __shared__ int bestk[32];
  const int tid  = threadIdx.x;
  const int tok0 = blockIdx.x * 32;
  const int ut = tid >> 3, uc = tid & 7;
  const int ty = tid >> 4, tx = tid & 15;
  const int t0 = ty * 2;
#pragma unroll
  for (int j = 0; j < 8; ++j) {
    int c4 = uc * 8 + j;
    float4 v = *(const float4*)&x[(size_t)(tok0 + ut) * D_ + c4 * 4];
    rs4[ut * 64 + (c4 ^ ((ut >> 2) & 3))] = v;
  }
  __syncthreads();
  float lsq = 0.f;
  for (int q = 0; q < Q_; ++q) {
    const float* cbq = cb + (size_t)q * K_ * D_;
    const float* cnq = cn + q * K_;
    float v1[2], v2[2]; int k1[2], k2[2];
#pragma unroll
    for (int i = 0; i < 2; ++i) { v1[i] = v2[i] = 3.4e38f; k1[i] = k2[i] = 0x7FFFFFFF; }
    for (int nc = 0; nc < 16; ++nc) {
      float acc[2][4];
#pragma unroll
      for (int i = 0; i < 2; ++i)
#pragma unroll
        for (int j = 0; j < 4; ++j) acc[i][j] = 0.f;
      for (int dc = 0; dc < 4; ++dc) {
        __syncthreads();
#pragma unroll
        for (int i = 0; i < 4; ++i) {
          int f = i * 256 + tid;
          int row = f >> 4, c = f & 15;
          float4 v = *(const float4*)&cbq[(size_t)(nc * 64 + row) * D_ + dc * 64 + c * 4];
          cbt[row * 16 + (c ^ (row >> 2))] = v;
        }
        __syncthreads();
#pragma unroll
        for (int d4 = 0; d4 < 16; ++d4) {
          float4 a[2], b[4];
#pragma unroll
          for (int i = 0; i < 2; ++i) {
            int t = t0 + i;
            int c4 = dc * 16 + d4;
            a[i] = rs4[t * 64 + (c4 ^ ((t >> 2) & 3))];
          }
#pragma unroll
          for (int j = 0; j < 4; ++j) {
            int row = tx * 4 + j;
            b[j] = cbt[row * 16 + (d4 ^ tx)];
          }
#pragma unroll
          for (int i = 0; i < 2; ++i)
#pragma unroll
            for (int j = 0; j < 4; ++j)
              acc[i][j] += a[i].x * b[j].x + a[i].y * b[j].y +
                           a[i].z * b[j].z + a[i].w * b[j].w;
        }
      }
#pragma unroll
      for (int j = 0; j < 4; ++j) {
        int k = nc * 64 + tx * 4 + j;
        float c2 = cnq[k];
#pragma unroll
        for (int i = 0; i < 2; ++i) {
          float s = c2 - 2.f * acc[i][j];
          if (lt2(s, k, v1[i], k1[i])) { v2[i] = v1[i]; k2[i] = k1[i]; v1[i] = s; k1[i] = k; }
          else if (lt2(s, k, v2[i], k2[i])) { v2[i] = s; k2[i] = k; }
        }
      }
    }
#pragma unroll
    for (int i = 0; i < 2; ++i) {
      float a1 = v1[i]; int b1 = k1[i];
      float a2 = v2[i]; int b2 = k2[i];
#pragma unroll
      for (int off = 1; off < 16; off <<= 1) {
        float o1 = __shfl_xor(a1, off); int p1 = __shfl_xor(b1, off);
        float o2 = __shfl_xor(a2, off); int p2 = __shfl_xor(b2, off);
        if (lt2(o1, p1, a1, b1)) {
          if (lt2(a1, b1, o2, p2)) { a2 = a1; b2 = b1; } else { a2 = o2; b2 = p2; }
          a1 = o1; b1 = p1;
        } else if (lt2(o1, p1, a2, b2)) { a2 = o1; b2 = p1; }
      }
      if (tx == 0) {
        int t = t0 + i;
        int kk = b1 & (K_ - 1);
        if (a2 - a1 < MARGIN_V8) {
          int kb = b2 & (K_ - 1);
          const float* rowA = cbq + (size_t)kk * D_;
          const float* rowB = cbq + (size_t)kb * D_;
          const float* rsf = (const float*)rs4;
          const int tt = t;
          auto rd = [&](int d) -> float {
            return rsf[(tt * 64 + ((d >> 2) ^ ((tt >> 2) & 3))) * 4 + (d & 3)];
          };
          float A  = np_sum256([&](int d) { float r = rd(d); return __fmul_rn(r, r); });
          float Ea = np_einsum256([&](int d) { return __fmul_rn(rd(d), rowA[d]); });
          float Ca = np_sum256([&](int d) { float c = rowA[d]; return __fmul_rn(c, c); });
          float Eb = np_einsum256([&](int d) { return __fmul_rn(rd(d), rowB[d]); });
          float Cb = np_sum256([&](int d) { float c = rowB[d]; return __fmul_rn(c, c); });
          float da = __fadd_rn(__fsub_rn(A, __fmul_rn(2.f, Ea)), Ca);
          float db = __fadd_rn(__fsub_rn(A, __fmul_rn(2.f, Eb)), Cb);
          if (db < da || (db == da && kb < kk)) kk = kb;
        }
        bestk[t] = kk;
        out[QUANT_N + q * NTOK + tok0 + t] = (float)kk;
      }
    }
    __syncthreads();
    {
      int kk = bestk[ut] & (K_ - 1);
      const float* crow = cbq + (size_t)kk * D_;
#pragma unroll
      for (int j = 0; j < 8; ++j) {
        int c4 = uc * 8 + j;
        float4 cv = *(const float4*)&crow[c4 * 4];
        int slot = ut * 64 + (c4 ^ ((ut >> 2) & 3));
        float4 rv = rs4[slot];
        rv.x -= cv.x; rv.y -= cv.y; rv.z -= cv.z; rv.w -= cv.w;
        rs4[slot] = rv;
        lsq += rv.x * rv.x + rv.y * rv.y + rv.z * rv.z + rv.w * rv.w;
      }
    }
  }
  __syncthreads();
#pragma unroll
  for (int j = 0; j < 8; ++j) {
    int c4 = uc * 8 + j;
    float4 xv = *(const float4*)&x[(size_t)(tok0 + ut) * D_ + c4 * 4];
    float4 rv = rs4[ut * 64 + (c4 ^ ((ut >> 2) & 3))];
    float4 o;
    o.x = xv.x - rv.x; o.y = xv.y - rv.y;
    o.z = xv.z - rv.z; o.w = xv.w - rv.w;
    *(float4*)&out[(size_t)(tok0 + ut) * D_ + c4 * 4] = o;
  }
#pragma unroll
  for (int off = 32; off; off >>= 1) lsq += __shfl_xor(lsq, off);
  if ((tid & 63) == 0) atomicAdd(loss_ws, lsq);
}

// ---------------------------------------------------------------------------
__global__ void rvq_finalize(const float* __restrict__ ws,
                             float* __restrict__ out) {
  if (threadIdx.x == 0) {
    float loss = 1.25f * ws[0] * (1.0f / (float)QUANT_N);
#pragma unroll
    for (int i = 0; i < 4; ++i) out[LOSS_OFF + i] = loss;
  }
}

// ---------------------------------------------------------------------------
extern "C" void kernel_launch(void* const* d_in, const int* in_sizes, int n_in,
                              void* d_out, int out_size, void* d_ws, size_t ws_size,
                              hipStream_t stream) {
  const float* x  = (const float*)d_in[0];
  const float* cb = (const float*)d_in[1];
  if (n_in >= 2 && in_sizes[0] != QUANT_N) {
    x  = (const float*)d_in[1];
    cb = (const float*)d_in[0];
  }
  float* out = (float*)d_out;

  float* ws = (float*)d_ws;
  float* cn = ws + 64;                                  // 4096 f32
  _Float16* cbh = (_Float16*)(ws + 64 + Q_ * K_);       // 2 MB fp16 codebook
  size_t need = (size_t)(64 + Q_ * K_) * 4 + (size_t)Q_ * K_ * D_ * 2 + 256;

  rvq_zero<<<1, 1, 0, stream>>>(ws);
  if (ws_size >= need) {
    rvq_prep<<<Q_ * K_ / 4, 256, 0, stream>>>(cb, cn, cbh);
    rvq_mfma3<<<NTOK / 64, 256, 0, stream>>>(x, cb, cn, cbh, out, ws);
  } else {
    rvq_cnorm<<<Q_ * K_ / 4, 256, 0, stream>>>(cb, cn);
    rvq_main_v8<<<NTOK / 32, 256, 0, stream>>>(x, cb, cn, out, ws);
  }
  rvq_finalize<<<1, 64, 0, stream>>>(ws, out);
}

// Round 13
// 569.463 us; speedup vs baseline: 1.2983x; 1.2983x over previous
//
#include <hip/hip_runtime.h>

// RVQTokenizer: x[16,2048,256] f32, codebooks[4,1024,256] f32.
// Outputs (flat f32): quant[16,2048,256], indices[4,16,2048] (as float),
// 4 scalar losses (all = total vq_loss).
#define B_    16
#define T_    2048
#define D_    256
#define Q_    4
#define K_    1024
#define NTOK  (B_ * T_)            // 32768
#define QUANT_N (NTOK * D_)        // 8388608
#define IDX_N   (Q_ * NTOK)        // 131072
#define LOSS_OFF (QUANT_N + IDX_N) // 8519680
#define MARGIN_V8   0.03f          // fp32-coarse window (fallback kernel)

// u32 score-key packing (verified PASS round 12):
// key = clamp(s*2048 + 2^21, [0, 2^22-1]) << 10 | n
#define KSCALE 2048.0f
#define KBIAS  2097152.0f          // 1<<21
#define KMAXF  4194303.0f          // (1<<22)-1
#define MKEY   123u                // 0.06 * 2048 adjudication window

typedef __attribute__((ext_vector_type(8))) _Float16 f16x8;
typedef __attribute__((ext_vector_type(4))) _Float16 f16x4;
typedef __attribute__((ext_vector_type(4))) float    f32x4;
typedef unsigned int u32;

__device__ __forceinline__ bool lt2(float v, int k, float w, int m) {
  return v < w || (v == w && k < m);
}
__device__ __forceinline__ u32 umn(u32 a, u32 b) { return a < b ? a : b; }
__device__ __forceinline__ u32 umx(u32 a, u32 b) { return a > b ? a : b; }
__device__ __forceinline__ int imn(int a, int b) { return a < b ? a : b; }

// insert key into sorted min-3 (t0<=t1<=t2): 5 min/max ops
__device__ __forceinline__ void kins3(u32& t0, u32& t1, u32& t2, u32 key) {
  u32 m0 = umx(t0, key); t0 = umn(t0, key);
  u32 m1 = umx(t1, m0);  t1 = umn(t1, m0);
  t2 = umn(t2, m1);
}

// ---------------------------------------------------------------------------
// Bit-exact numpy emulation (verified PASS in rounds 8-12).
template <typename F>
__device__ __forceinline__ float np_sum256(F p) {
  float half[2];
#pragma unroll
  for (int h = 0; h < 2; ++h) {
    const int base = h * 128;
    float s[16];
#pragma unroll
    for (int l = 0; l < 16; ++l) {
      float t01 = __fadd_rn(p(base + l),      p(base + 16 + l));
      float t23 = __fadd_rn(p(base + 32 + l), p(base + 48 + l));
      float t45 = __fadd_rn(p(base + 64 + l), p(base + 80 + l));
      float t67 = __fadd_rn(p(base + 96 + l), p(base + 112 + l));
      s[l] = __fadd_rn(__fadd_rn(t01, t23), __fadd_rn(t45, t67));
    }
#pragma unroll
    for (int w = 8; w >= 1; w >>= 1)
#pragma unroll
      for (int l = 0; l < w; ++l) s[l] = __fadd_rn(s[l], s[l + w]);
    half[h] = s[0];
  }
  return __fadd_rn(half[0], half[1]);
}

template <typename F>
__device__ __forceinline__ float np_einsum256(F p) {
  float v[4] = {0.f, 0.f, 0.f, 0.f};
#pragma unroll
  for (int c = 0; c < 16; ++c) {
#pragma unroll
    for (int l = 0; l < 4; ++l) {
      int d0 = c * 16 + l;
      float t = __fadd_rn(p(d0 + 12), v[l]);
      t = __fadd_rn(p(d0 + 8), t);
      t = __fadd_rn(p(d0 + 4), t);
      v[l] = __fadd_rn(p(d0), t);
    }
  }
  return __fadd_rn(__fadd_rn(v[0], v[1]), __fadd_rn(v[2], v[3]));
}

__global__ void rvq_zero(float* __restrict__ ws) { ws[0] = 0.f; }

// ---------------------------------------------------------------------------
// Prep: cn[k]=||c_k||^2 (coarse only) and fp16 codebook copy.
__global__ __launch_bounds__(256) void rvq_prep(const float* __restrict__ cb,
                                                float* __restrict__ cn,
                                                _Float16* __restrict__ cbh) {
  int k = blockIdx.x * 4 + (threadIdx.x >> 6);   // 0..4095
  int l = threadIdx.x & 63;
  const float* row = cb + (size_t)k * D_;
  float s = 0.f;
#pragma unroll
  for (int j = 0; j < 4; ++j) { float v = row[l + 64 * j]; s += v * v; }
#pragma unroll
  for (int off = 32; off; off >>= 1) s += __shfl_xor(s, off);
  if (l == 0) cn[k] = s;
  int gid = blockIdx.x * 256 + threadIdx.x;      // 0..262143
  float4 v = *(const float4*)&cb[(size_t)gid * 4];
  f16x4 h;
  h[0] = (_Float16)v.x; h[1] = (_Float16)v.y;
  h[2] = (_Float16)v.z; h[3] = (_Float16)v.w;
  *(f16x4*)&cbh[(size_t)gid * 4] = h;
}

// load B fragments for codeword group Nt (8 x f16x8 per lane)
__device__ __forceinline__ void ldB(const _Float16* __restrict__ cbhq,
                                    int Nt, int l15, int lg, f16x8* bb) {
  const _Float16* brow = cbhq + (size_t)(Nt * 16 + l15) * D_ + lg * 8;
#pragma unroll
  for (int ks = 0; ks < 8; ++ks) bb[ks] = *(const f16x8*)&brow[ks * 32];
}

// score one codeword group: 4 independent MFMA chains of 4, u32-key top-3.
#define SCORE_GRP(bb, grp, cval)                                              \
  do {                                                                        \
    const int n_ = (grp) * 16 + l15;                                          \
    f32x4 h0 = {0.f,0.f,0.f,0.f}, h1 = {0.f,0.f,0.f,0.f};                     \
    f32x4 e0 = {0.f,0.f,0.f,0.f}, e1 = {0.f,0.f,0.f,0.f};                     \
    _Pragma("unroll")                                                         \
    for (int ks = 0; ks < 4; ++ks) {                                          \
      h0 = __builtin_amdgcn_mfma_f32_16x16x32_f16(Ah[ks],     bb[ks],     h0, 0, 0, 0); \
      h1 = __builtin_amdgcn_mfma_f32_16x16x32_f16(Ah[ks + 4], bb[ks + 4], h1, 0, 0, 0); \
      e0 = __builtin_amdgcn_mfma_f32_16x16x32_f16(Al[ks],     bb[ks],     e0, 0, 0, 0); \
      e1 = __builtin_amdgcn_mfma_f32_16x16x32_f16(Al[ks + 4], bb[ks + 4], e1, 0, 0, 0); \
    }                                                                         \
    float c2b_ = __builtin_fmaf((cval), KSCALE, KBIAS);                       \
    _Pragma("unroll")                                                         \
    for (int r = 0; r < 4; ++r) {                                             \
      float sum_ = (h0[r] + h1[r]) + (e0[r] + e1[r]);                         \
      float kf_ = __builtin_fmaf(sum_, -2.f * KSCALE, c2b_);                  \
      u32 kv_ = (u32)fminf(fmaxf(kf_, 0.f), KMAXF);                           \
      kins3(t0[r], t1[r], t2[r], (kv_ << 10) | (u32)n_);                      \
    }                                                                         \
  } while (0)

// ---------------------------------------------------------------------------
// MFMA RVQ. 64 tokens/block, 256 threads (4 waves, 1 M-tile each).
// waves_per_eu(2,2): LDS pins 2 waves/SIMD anyway -> give RA the full
// 256-VGPR budget so the b0/b1/b2 prefetch buffers stay in registers.
__global__ __attribute__((amdgpu_waves_per_eu(2, 2)))
__launch_bounds__(256, 2) void rvq_mfma(const float* __restrict__ x,
                                        const float* __restrict__ cb,
                                        const float* __restrict__ cn,
                                        const _Float16* __restrict__ cbh,
                                        float* __restrict__ out,
                                        float* __restrict__ loss_ws) {
  __shared__ float rs[64 * 256];   // 64 KiB, linear [t][d]
  __shared__ int bestk[64];

  const int tid  = threadIdx.x;
  const int tok0 = blockIdx.x * 64;
  const int lane = tid & 63;
  const int wv   = tid >> 6;       // wave id = M-tile (tokens wv*16..+15)
  const int l15  = lane & 15;      // A-row / B-col / D-col index
  const int lg   = lane >> 4;      // k-group / D-row-group
  const int ut   = tid >> 2, uc = tid & 3;   // streaming: 4 threads per token

  // ---- load x -> rs -------------------------------------------------------
#pragma unroll
  for (int j = 0; j < 16; ++j) {
    int c4 = j * 4 + uc;
    *(float4*)&rs[ut * 256 + c4 * 4] =
        *(const float4*)&x[(size_t)(tok0 + ut) * D_ + c4 * 4];
  }
  __syncthreads();

  float lsq = 0.f;

  for (int q = 0; q < Q_; ++q) {
    const float*    cbq  = cb  + (size_t)q * K_ * D_;
    const float*    cnq  = cn  + q * K_;
    const _Float16* cbhq = cbh + (size_t)q * K_ * D_;

    // ---- A fragments (fp16 hi/lo) for this wave's 16 token rows ----------
    f16x8 Ah[8], Al[8];
    {
      const float* rrow = &rs[(wv * 16 + l15) * 256];
#pragma unroll
      for (int ks = 0; ks < 8; ++ks) {
        float4 v0 = *(const float4*)&rrow[ks * 32 + lg * 8];
        float4 v1 = *(const float4*)&rrow[ks * 32 + lg * 8 + 4];
        float vv[8] = {v0.x, v0.y, v0.z, v0.w, v1.x, v1.y, v1.z, v1.w};
        f16x8 h, l;
#pragma unroll
        for (int j = 0; j < 8; ++j) {
          _Float16 hj = (_Float16)vv[j];
          h[j] = hj;
          l[j] = (_Float16)(vv[j] - (float)hj);
        }
        Ah[ks] = h; Al[ks] = l;
      }
    }

    // ---- top-3 u32 keys: tokens m = wv*16 + lg*4 + r ----------------------
    u32 t0[4], t1[4], t2[4];
#pragma unroll
    for (int r = 0; r < 4; ++r) { t0[r] = t1[r] = t2[r] = 0xFFFFFFFFu; }

    // ---- coarse scoring, 2-deep pipeline (b0/b1/b2 static rotation),
    //      branch-free clamped prefetch, cn rotated 2 groups ahead ----------
    {
      f16x8 b0[8], b1[8], b2[8];
      float cA, cB, cC;
      ldB(cbhq, 0, l15, lg, b0); cA = cnq[l15];
      ldB(cbhq, 1, l15, lg, b1); cB = cnq[16 + l15];
      for (int p = 0; p < 21; ++p) {        // groups 3p, 3p+1, 3p+2
        const int g = 3 * p;
        ldB(cbhq, g + 2, l15, lg, b2); cC = cnq[(g + 2) * 16 + l15];
        SCORE_GRP(b0, g, cA);
        { int gn = imn(g + 3, 63); ldB(cbhq, gn, l15, lg, b0); cA = cnq[gn * 16 + l15]; }
        SCORE_GRP(b1, g + 1, cB);
        { int gn = imn(g + 4, 63); ldB(cbhq, gn, l15, lg, b1); cB = cnq[gn * 16 + l15]; }
        SCORE_GRP(b2, g + 2, cC);
      }
      SCORE_GRP(b0, 63, cA);                // loaded at p=20 (3*20+3)
    }

    // ---- merge top-3 across the 16 l15 lanes ------------------------------
#pragma unroll
    for (int r = 0; r < 4; ++r) {
#pragma unroll
      for (int off = 1; off < 16; off <<= 1) {
        u32 o0 = (u32)__shfl_xor((int)t0[r], off);
        u32 o1 = (u32)__shfl_xor((int)t1[r], off);
        u32 o2 = (u32)__shfl_xor((int)t2[r], off);
        kins3(t0[r], t1[r], t2[r], o0);
        kins3(t0[r], t1[r], t2[r], o1);
        kins3(t0[r], t1[r], t2[r], o2);
      }
    }

    // ---- leaders adjudicate (np-bit-exact) + write indices ----------------
    if (l15 == 0) {
#pragma unroll
      for (int r = 0; r < 4; ++r) {
        int t = wv * 16 + lg * 4 + r;     // local token
        int kk = (int)(t0[r] & 1023u);
        u32 s0 = t0[r] >> 10, s1 = t1[r] >> 10, s2 = t2[r] >> 10;
        if (s1 - s0 < MKEY) {
          const float* rsrow = &rs[t * 256];
          float A = np_sum256([&](int d) {
            float rr = rsrow[d]; return __fmul_rn(rr, rr);
          });
          int cand[3]; int nc2 = 1;
          cand[0] = kk;
          cand[nc2++] = (int)(t1[r] & 1023u);
          if (s2 - s0 < MKEY) cand[nc2++] = (int)(t2[r] & 1023u);
          float bd = 3.4e38f; int bk2 = 0x7FFFFFFF;
          for (int i = 0; i < nc2; ++i) {
            const float* crow = cbq + (size_t)cand[i] * D_;
            float E = np_einsum256([&](int d) {
              return __fmul_rn(rsrow[d], crow[d]);
            });
            float C = np_sum256([&](int d) {
              float cc = crow[d]; return __fmul_rn(cc, cc);
            });
            float dd = __fadd_rn(__fsub_rn(A, __fmul_rn(2.f, E)), C);
            if (dd < bd || (dd == bd && cand[i] < bk2)) { bd = dd; bk2 = cand[i]; }
          }
          kk = bk2;
        }
        bestk[t] = kk;
        out[QUANT_N + q * NTOK + tok0 + t] = (float)kk;
      }
    }
    __syncthreads();          // bestk visible; rs reads (A/adjudicate) done

    // ---- residual update + loss -------------------------------------------
    {
      int kk = bestk[ut] & (K_ - 1);
      const float* crow = cbq + (size_t)kk * D_;
#pragma unroll
      for (int j = 0; j < 16; ++j) {
        int c4 = j * 4 + uc;
        float4 cv = *(const float4*)&crow[c4 * 4];
        float4 rv = *(float4*)&rs[ut * 256 + c4 * 4];
        rv.x -= cv.x; rv.y -= cv.y; rv.z -= cv.z; rv.w -= cv.w;
        *(float4*)&rs[ut * 256 + c4 * 4] = rv;
        lsq += rv.x * rv.x + rv.y * rv.y + rv.z * rv.z + rv.w * rv.w;
      }
    }
    __syncthreads();          // rs updated before next stage's A-read
  }

  // ---- quant = x - r_final -------------------------------------------------
#pragma unroll
  for (int j = 0; j < 16; ++j) {
    int c4 = j * 4 + uc;
    float4 xv = *(const float4*)&x[(size_t)(tok0 + ut) * D_ + c4 * 4];
    float4 rv = *(const float4*)&rs[ut * 256 + c4 * 4];
    float4 o;
    o.x = xv.x - rv.x; o.y = xv.y - rv.y;
    o.z = xv.z - rv.z; o.w = xv.w - rv.w;
    *(float4*)&out[(size_t)(tok0 + ut) * D_ + c4 * 4] = o;
  }

  // ---- loss: wave reduce + one atomic per wave -----------------------------
#pragma unroll
  for (int off = 32; off; off >>= 1) lsq += __shfl_xor(lsq, off);
  if ((tid & 63) == 0) atomicAdd(loss_ws, lsq);
}

// ---------------------------------------------------------------------------
// FALLBACK (round-8 kernel, verbatim): used only if ws is too small for cbh.
__global__ __launch_bounds__(256) void rvq_cnorm(const float* __restrict__ cb,
                                                 float* __restrict__ cn) {
  int k = blockIdx.x * 4 + (threadIdx.x >> 6);
  int l = threadIdx.x & 63;
  const float* row = cb + (size_t)k * D_;
  float s = 0.f;
#pragma unroll
  for (int j = 0; j < 4; ++j) { float v = row[l + 64 * j]; s += v * v; }
#pragma unroll
  for (int off = 32; off; off >>= 1) s += __shfl_xor(s, off);
  if (l == 0) cn[k] = s;
}

__global__ __launch_bounds__(256, 2) void rvq_main_v8(const float* __restrict__ x,
                                                      const float* __restrict__ cb,
                                                      const float* __restrict__ cn,
                                                      float* __restrict__ out,
                                                      float* __restrict__ loss_ws) {
  __shared__ float4 rs4[32 * 64];
  __shared__ float4 cbt[64 * 16];
  __shared__ int bestk[32];
  const int tid  = threadIdx.x;
  const int tok0 = blockIdx.x * 32;
  const int ut = tid >> 3, uc = tid & 7;
  const int ty = tid >> 4, tx = tid & 15;
  const int t0 = ty * 2;
#pragma unroll
  for (int j = 0; j < 8; ++j) {
    int c4 = uc * 8 + j;
    float4 v = *(const float4*)&x[(size_t)(tok0 + ut) * D_ + c4 * 4];
    rs4[ut * 64 + (c4 ^ ((ut >> 2) & 3))] = v;
  }
  __syncthreads();
  float lsq = 0.f;
  for (int q = 0; q < Q_; ++q) {
    const float* cbq = cb + (size_t)q * K_ * D_;
    const float* cnq = cn + q * K_;
    float v1[2], v2[2]; int k1[2], k2[2];
#pragma unroll
    for (int i = 0; i < 2; ++i) { v1[i] = v2[i] = 3.4e38f; k1[i] = k2[i] = 0x7FFFFFFF; }
    for (int nc = 0; nc < 16; ++nc) {
      float acc[2][4];
#pragma unroll
      for (int i = 0; i < 2; ++i)
#pragma unroll
        for (int j = 0; j < 4; ++j) acc[i][j] = 0.f;
      for (int dc = 0; dc < 4; ++dc) {
        __syncthreads();
#pragma unroll
        for (int i = 0; i < 4; ++i) {
          int f = i * 256 + tid;
          int row = f >> 4, c = f & 15;
          float4 v = *(const float4*)&cbq[(size_t)(nc * 64 + row) * D_ + dc * 64 + c * 4];
          cbt[row * 16 + (c ^ (row >> 2))] = v;
        }
        __syncthreads();
#pragma unroll
        for (int d4 = 0; d4 < 16; ++d4) {
          float4 a[2], b[4];
#pragma unroll
          for (int i = 0; i < 2; ++i) {
            int t = t0 + i;
            int c4 = dc * 16 + d4;
            a[i] = rs4[t * 64 + (c4 ^ ((t >> 2) & 3))];
          }
#pragma unroll
          for (int j = 0; j < 4; ++j) {
            int row = tx * 4 + j;
            b[j] = cbt[row * 16 + (d4 ^ tx)];
          }
#pragma unroll
          for (int i = 0; i < 2; ++i)
#pragma unroll
            for (int j = 0; j < 4; ++j)
              acc[i][j] += a[i].x * b[j].x + a[i].y * b[j].y +
                           a[i].z * b[j].z + a[i].w * b[j].w;
        }
      }
#pragma unroll
      for (int j = 0; j < 4; ++j) {
        int k = nc * 64 + tx * 4 + j;
        float c2 = cnq[k];
#pragma unroll
        for (int i = 0; i < 2; ++i) {
          float s = c2 - 2.f * acc[i][j];
          if (lt2(s, k, v1[i], k1[i])) { v2[i] = v1[i]; k2[i] = k1[i]; v1[i] = s; k1[i] = k; }
          else if (lt2(s, k, v2[i], k2[i])) { v2[i] = s; k2[i] = k; }
        }
      }
    }
#pragma unroll
    for (int i = 0; i < 2; ++i) {
      float a1 = v1[i]; int b1 = k1[i];
      float a2 = v2[i]; int b2 = k2[i];
#pragma unroll
      for (int off = 1; off < 16; off <<= 1) {
        float o1 = __shfl_xor(a1, off); int p1 = __shfl_xor(b1, off);
        float o2 = __shfl_xor(a2, off); int p2 = __shfl_xor(b2, off);
        if (lt2(o1, p1, a1, b1)) {
          if (lt2(a1, b1, o2, p2)) { a2 = a1; b2 = b1; } else { a2 = o2; b2 = p2; }
          a1 = o1; b1 = p1;
        } else if (lt2(o1, p1, a2, b2)) { a2 = o1; b2 = p1; }
      }
      if (tx == 0) {
        int t = t0 + i;
        int kk = b1 & (K_ - 1);
        if (a2 - a1 < MARGIN_V8) {
          int kb = b2 & (K_ - 1);
          const float* rowA = cbq + (size_t)kk * D_;
          const float* rowB = cbq + (size_t)kb * D_;
          const float* rsf = (const float*)rs4;
          const int tt = t;
          auto rd = [&](int d) -> float {
            return rsf[(tt * 64 + ((d >> 2) ^ ((tt >> 2) & 3))) * 4 + (d & 3)];
          };
          float A  = np_sum256([&](int d) { float r = rd(d); return __fmul_rn(r, r); });
          float Ea = np_einsum256([&](int d) { return __fmul_rn(rd(d), rowA[d]); });
          float Ca = np_sum256([&](int d) { float c = rowA[d]; return __fmul_rn(c, c); });
          float Eb = np_einsum256([&](int d) { return __fmul_rn(rd(d), rowB[d]); });
          float Cb = np_sum256([&](int d) { float c = rowB[d]; return __fmul_rn(c, c); });
          float da = __fadd_rn(__fsub_rn(A, __fmul_rn(2.f, Ea)), Ca);
          float db = __fadd_rn(__fsub_rn(A, __fmul_rn(2.f, Eb)), Cb);
          if (db < da || (db == da && kb < kk)) kk = kb;
        }
        bestk[t] = kk;
        out[QUANT_N + q * NTOK + tok0 + t] = (float)kk;
      }
    }
    __syncthreads();
    {
      int kk = bestk[ut] & (K_ - 1);
      const float* crow = cbq + (size_t)kk * D_;
#pragma unroll
      for (int j = 0; j < 8; ++j) {
        int c4 = uc * 8 + j;
        float4 cv = *(const float4*)&crow[c4 * 4];
        int slot = ut * 64 + (c4 ^ ((ut >> 2) & 3));
        float4 rv = rs4[slot];
        rv.x -= cv.x; rv.y -= cv.y; rv.z -= cv.z; rv.w -= cv.w;
        rs4[slot] = rv;
        lsq += rv.x * rv.x + rv.y * rv.y + rv.z * rv.z + rv.w * rv.w;
      }
    }
  }
  __syncthreads();
#pragma unroll
  for (int j = 0; j < 8; ++j) {
    int c4 = uc * 8 + j;
    float4 xv = *(const float4*)&x[(size_t)(tok0 + ut) * D_ + c4 * 4];
    float4 rv = rs4[ut * 64 + (c4 ^ ((ut >> 2) & 3))];
    float4 o;
    o.x = xv.x - rv.x; o.y = xv.y - rv.y;
    o.z = xv.z - rv.z; o.w = xv.w - rv.w;
    *(float4*)&out[(size_t)(tok0 + ut) * D_ + c4 * 4] = o;
  }
#pragma unroll
  for (int off = 32; off; off >>= 1) lsq += __shfl_xor(lsq, off);
  if ((tid & 63) == 0) atomicAdd(loss_ws, lsq);
}

// ---------------------------------------------------------------------------
__global__ void rvq_finalize(const float* __restrict__ ws,
                             float* __restrict__ out) {
  if (threadIdx.x == 0) {
    float loss = 1.25f * ws[0] * (1.0f / (float)QUANT_N);
#pragma unroll
    for (int i = 0; i < 4; ++i) out[LOSS_OFF + i] = loss;
  }
}

// ---------------------------------------------------------------------------
extern "C" void kernel_launch(void* const* d_in, const int* in_sizes, int n_in,
                              void* d_out, int out_size, void* d_ws, size_t ws_size,
                              hipStream_t stream) {
  const float* x  = (const float*)d_in[0];
  const float* cb = (const float*)d_in[1];
  if (n_in >= 2 && in_sizes[0] != QUANT_N) {
    x  = (const float*)d_in[1];
    cb = (const float*)d_in[0];
  }
  float* out = (float*)d_out;

  float* ws = (float*)d_ws;
  float* cn = ws + 64;                                  // 4096 f32
  _Float16* cbh = (_Float16*)(ws + 64 + Q_ * K_);       // 2 MB fp16 codebook
  size_t need = (size_t)(64 + Q_ * K_) * 4 + (size_t)Q_ * K_ * D_ * 2 + 256;

  rvq_zero<<<1, 1, 0, stream>>>(ws);
  if (ws_size >= need) {
    rvq_prep<<<Q_ * K_ / 4, 256, 0, stream>>>(cb, cn, cbh);
    rvq_mfma<<<NTOK / 64, 256, 0, stream>>>(x, cb, cn, cbh, out, ws);
  } else {
    rvq_cnorm<<<Q_ * K_ / 4, 256, 0, stream>>>(cb, cn);
    rvq_main_v8<<<NTOK / 32, 256, 0, stream>>>(x, cb, cn, out, ws);
  }
  rvq_finalize<<<1, 64, 0, stream>>>(ws, out);
}